// Round 5
// baseline (471.519 us; speedup 1.0000x reference)
//
#include <hip/hip_runtime.h>
#include <hip/hip_bf16.h>
#include <math.h>

// Problem constants
#define BB 256
#define TT 256
#define EE 384
#define HH 6
#define DD 64

typedef __attribute__((ext_vector_type(8))) short bf16x8;
typedef __attribute__((ext_vector_type(4))) float f32x4;

__device__ inline unsigned short f2bf(float f) {
  unsigned int u = __builtin_bit_cast(unsigned int, f);
  u += 0x7fffu + ((u >> 16) & 1u);
  return (unsigned short)(u >> 16);
}

__device__ __forceinline__ void g2l16(const unsigned short* g, unsigned short* l) {
  // async global -> LDS, 16B per lane; LDS dest = wave-uniform base + lane*16
  __builtin_amdgcn_global_load_lds(
      (const __attribute__((address_space(1))) void*)g,
      (__attribute__((address_space(3))) void*)l, 16, 0, 0);
}

// ---------------------------------------------------------------------------
// Kernel 0: fused prep. Blocks [0, 24576): fp32->bf16 convert of x.
// Blocks [24576, 26880): weight prep Wt[1536][384] bf16:
//   rows 0..1151:  Wt[mat*384 + h*64 + d][e] = W{q,k,v}[h][e][d]
//   rows 1152..1535: Wt[1152 + n][k] = Wo[k][n]
// ---------------------------------------------------------------------------
#define CVT_BLOCKS 24576   // (BB*TT*EE/4) / 256
__global__ __launch_bounds__(256) void prep_kernel(const float* __restrict__ x,
                                                   const float* __restrict__ Wq,
                                                   const float* __restrict__ Wk,
                                                   const float* __restrict__ Wv,
                                                   const float* __restrict__ Wo,
                                                   unsigned short* __restrict__ xb,
                                                   unsigned short* __restrict__ Wt) {
  int bid = blockIdx.x;
  if (bid < CVT_BLOCKS) {
    int i = bid * 256 + threadIdx.x;      // exact: CVT_BLOCKS*256 == n4
    float4 f = ((const float4*)x)[i];
    ushort4 o;
    o.x = f2bf(f.x); o.y = f2bf(f.y); o.z = f2bf(f.z); o.w = f2bf(f.w);
    ((ushort4*)xb)[i] = o;
  } else {
    int idx = (bid - CVT_BLOCKS) * 256 + threadIdx.x;  // exact: 2304*256 == 1536*384
    int n = idx / 384, k = idx % 384;
    float val;
    if (n < 1152) {
      int mat = n / 384;
      int c = n % 384;
      int h = c >> 6, d = c & 63;
      const float* W = (mat == 0) ? Wq : (mat == 1 ? Wk : Wv);
      val = W[((size_t)h * EE + k) * DD + d];
    } else {
      int c = n - 1152;
      val = Wo[(size_t)k * EE + c];
    }
    Wt[idx] = f2bf(val);
  }
}

// ---------------------------------------------------------------------------
// Shared GEMM-tile macros: 128x128 tile, BK=64, XOR-swizzled LDS,
// double-buffered (2-phase pipeline).  Both operands via global_load_lds.
// Buffer b: As @ smem + b*32768 (bytes), Bs = As + 16384 B.
// ---------------------------------------------------------------------------
#define STAGE_T(buf, k0, Bsrc)                                                  \
  do {                                                                          \
    unsigned short* As_ = (unsigned short*)(smem + (buf) * 32768);              \
    unsigned short* Bs_ = As_ + 8192;                                           \
    _Pragma("unroll") for (int i = 0; i < 4; ++i) {                             \
      int rl = rl_base + i * 8;                                                 \
      int gcb = sb ^ (rl & 7);                                                  \
      g2l16(A + (size_t)(m0 + rl) * EE + (k0) + gcb * 8,                        \
            &As_[(wave * 32 + i * 8) * 64]);                                    \
    }                                                                           \
    _Pragma("unroll") for (int i = 0; i < 4; ++i) {                             \
      int rl = rl_base + i * 8;                                                 \
      int gcb = sb ^ (rl & 7);                                                  \
      g2l16((Bsrc) + (size_t)(n0 + rl) * EE + (k0) + gcb * 8,                   \
            &Bs_[(wave * 32 + i * 8) * 64]);                                    \
    }                                                                           \
  } while (0)

#define COMPUTE_T(buf)                                                          \
  do {                                                                          \
    const unsigned short* As_ = (const unsigned short*)(smem + (buf) * 32768);  \
    const unsigned short* Bs_ = As_ + 8192;                                     \
    _Pragma("unroll") for (int kc = 0; kc < 2; ++kc) {                          \
      bf16x8 af[4], bfr[4];                                                     \
      _Pragma("unroll") for (int mi = 0; mi < 4; ++mi)                          \
          af[mi] = *(const bf16x8*)&As_[(wm + mi * 16 + l15) * 64 +             \
                                        ((kc * 4 + quad) ^ xs) * 8];            \
      _Pragma("unroll") for (int ni = 0; ni < 4; ++ni)                          \
          bfr[ni] = *(const bf16x8*)&Bs_[(wn + ni * 16 + l15) * 64 +            \
                                         ((kc * 4 + quad) ^ xs) * 8];           \
      _Pragma("unroll") for (int mi = 0; mi < 4; ++mi)                          \
          _Pragma("unroll") for (int ni = 0; ni < 4; ++ni)                      \
              acc[mi][ni] = __builtin_amdgcn_mfma_f32_16x16x32_bf16(            \
                  af[mi], bfr[ni], acc[mi][ni], 0, 0, 0);                       \
    }                                                                           \
  } while (0)

// ---------------------------------------------------------------------------
// Kernel 1: fused QKV GEMM.  C[65536, 1152] = xb @ [Wq|Wk|Wv]  (bf16 MFMA)
// XCD-swizzled 1-D grid (4608 = 8 XCD * 64 m-tiles * 9 n-tiles): each XCD owns
// 64 contiguous m-tiles, iterating all 9 n-tiles per m-tile -> A-tile stays in
// that XCD's L2 across its 9 consumers.
// n-tiles 0..2 -> q (pre-scaled 1/8); 3..5 -> k; 6..8 -> v transposed [B,H,D,T].
// ---------------------------------------------------------------------------
__global__ __launch_bounds__(256, 2) void qkv128_kernel(const unsigned short* __restrict__ A,
                                                        const unsigned short* __restrict__ Wt,
                                                        unsigned short* __restrict__ q,
                                                        unsigned short* __restrict__ k,
                                                        unsigned short* __restrict__ v) {
  // bijective XCD swizzle: L = xcd + 8*j, j = mtile_local*9 + bx
  const int L = blockIdx.x;
  const int xcd = L & 7;
  const int j = L >> 3;                 // 0..575
  const int mt = xcd * 64 + j / 9;      // 0..511
  const int bx = j % 9;                 // n-tile
  const int m0 = mt * 128;
  const int n0 = bx * 128;

  __shared__ char smem[65536];
  unsigned short* bounce = (unsigned short*)smem;  // [64][136] after mainloop

  const int tid = threadIdx.x;
  const int wave = tid >> 6, lane = tid & 63;
  const int l15 = lane & 15, quad = lane >> 4;
  const int wm = (wave & 1) * 64, wn = (wave >> 1) * 64;
  const int xs = l15 & 7;

  f32x4 acc[4][4];
#pragma unroll
  for (int i = 0; i < 4; ++i)
#pragma unroll
    for (int jj = 0; jj < 4; ++jj) acc[i][jj] = (f32x4){0.f, 0.f, 0.f, 0.f};

  const int rl_base = wave * 32 + (lane >> 3);
  const int sb = lane & 7;

  // 2-phase pipeline: prologue stage, then {prefetch next | compute cur}
  STAGE_T(0, 0, Wt);
  __syncthreads();                       // vmcnt(0) drain + barrier
#pragma unroll
  for (int it = 0; it < 6; ++it) {
    if (it < 5) STAGE_T((it & 1) ^ 1, (it + 1) * 64, Wt);
    COMPUTE_T(it & 1);
    __syncthreads();                     // reads of cur done; next buf landed
  }

  const int b = m0 >> 8;          // 128-row tile stays within one batch (T=256)
  const int t0 = m0 & 255;

  if (bx < 6) {
    // q / k : [B,H,T,D].  q gets the softmax scale folded in (fp32, pre-round).
    unsigned short* outp = (bx < 3) ? q : k;
    const float qs = (bx < 3) ? 0.125f : 1.0f;
    const int cmbase = n0 - (bx < 3 ? 0 : 384);
#pragma unroll
    for (int ni = 0; ni < 4; ++ni) {
      int c = cmbase + wn + ni * 16 + l15;   // 0..383 within mat
      int h = c >> 6, d = c & 63;
#pragma unroll
      for (int mi = 0; mi < 4; ++mi)
#pragma unroll
        for (int r = 0; r < 4; ++r) {
          int t = t0 + wm + mi * 16 + quad * 4 + r;
          outp[(((size_t)b * HH + h) * TT + t) * DD + d] = f2bf(acc[mi][ni][r] * qs);
        }
    }
  } else {
    // v : transpose to [B,H,D,T] via LDS bounce, one 64-col half (one head) per pass
#pragma unroll
    for (int pass = 0; pass < 2; ++pass) {
      __syncthreads();
      if ((wave >> 1) == pass) {
#pragma unroll
        for (int ni = 0; ni < 4; ++ni) {
          int cl = ni * 16 + l15;            // d within head
#pragma unroll
          for (int mi = 0; mi < 4; ++mi)
#pragma unroll
            for (int r = 0; r < 4; ++r) {
              int rloc = wm + mi * 16 + quad * 4 + r;   // t within tile
              bounce[cl * 136 + rloc] = f2bf(acc[mi][ni][r]);
            }
        }
      }
      __syncthreads();
      int h = (bx - 6) * 2 + pass;
      int d = tid >> 2;
      int tb = (tid & 3) * 32;
      unsigned short* vdst = v + (((size_t)b * HH + h) * DD + d) * TT + t0 + tb;
      const unsigned short* bsrc = &bounce[d * 136 + tb];
#pragma unroll
      for (int jj = 0; jj < 4; ++jj)
        *(uint4*)(vdst + jj * 8) = *(const uint4*)(bsrc + jj * 8);
    }
  }
}

// ---------------------------------------------------------------------------
// Kernel 2: flash-style causal attention — R5: NO K/V LDS staging.
// K/V are L2/L3-resident (FETCH~0 measured); fragments are read per-MFMA
// directly from global (V pre-transposed upstream). All waves in a block read
// identical K/V fragments -> L1 x4 reuse. Ps stays wave-private in LDS.
// ZERO __syncthreads: waves fully independent, self-paced.
// ---------------------------------------------------------------------------
__global__ __launch_bounds__(256) void attn_kernel(const unsigned short* __restrict__ q,
                                                   const unsigned short* __restrict__ k,
                                                   const unsigned short* __restrict__ v,
                                                   unsigned short* __restrict__ att) {
  const int L = blockIdx.x;
  const int xcd = L & 7;
  const int j = L >> 3;                  // 0..767
  const int bh = xcd * 192 + (j >> 2);   // 1536/8 = 192 bh per XCD
  const int q0 = (j & 3) * 64;
  const int b = bh / HH, h = bh % HH;

  __shared__ unsigned short Ps[64 * 72];

  const int tid = threadIdx.x;
  const int wave = tid >> 6, lane = tid & 63;
  const int l15 = lane & 15, quad = lane >> 4;
  const int koff = quad * 8;

  // Q fragments: wave-private, loop-invariant -> load once from global
  bf16x8 aq[2];
  {
    const unsigned short* qrow =
        q + ((size_t)bh * TT + q0 + wave * 16 + l15) * DD + koff;
    aq[0] = *(const bf16x8*)(qrow);
    aq[1] = *(const bf16x8*)(qrow + 32);
  }

  // per-lane fragment base pointers
  // K frag (ct,kc) of tile j0: kfb + (j0 + ct*16)*DD + kc*32
  const unsigned short* kfb = k + ((size_t)bh * TT + l15) * DD + koff;
  // V frag (dt,kc) of tile j0: vfb + (dt*16)*TT + j0 + kc*32
  const unsigned short* vfb = v + ((size_t)bh * DD + l15) * TT + koff;

  f32x4 o_acc[4] = {{0.f,0.f,0.f,0.f},{0.f,0.f,0.f,0.f},{0.f,0.f,0.f,0.f},{0.f,0.f,0.f,0.f}};
  float m_run[4] = {-INFINITY, -INFINITY, -INFINITY, -INFINITY};
  float l_run[4] = {0.f, 0.f, 0.f, 0.f};

  for (int j0 = 0; j0 <= q0; j0 += 64) {
    // K fragments straight from global (L2-hot; identical across the 4 waves)
    bf16x8 kb[8];
#pragma unroll
    for (int kc = 0; kc < 2; ++kc)
#pragma unroll
      for (int ct = 0; ct < 4; ++ct)
        kb[kc * 4 + ct] =
            *(const bf16x8*)(kfb + (size_t)(j0 + ct * 16) * DD + kc * 32);

    // QK^T (q pre-scaled by 1/8 upstream)
    f32x4 s_acc[4] = {{0.f,0.f,0.f,0.f},{0.f,0.f,0.f,0.f},{0.f,0.f,0.f,0.f},{0.f,0.f,0.f,0.f}};
    __builtin_amdgcn_s_setprio(1);
#pragma unroll
    for (int kc = 0; kc < 2; ++kc)
#pragma unroll
      for (int ct = 0; ct < 4; ++ct)
        s_acc[ct] = __builtin_amdgcn_mfma_f32_16x16x32_bf16(aq[kc], kb[kc * 4 + ct],
                                                            s_acc[ct], 0, 0, 0);
    __builtin_amdgcn_s_setprio(0);

    // V fragments issued now -> latency hides under the softmax below
    bf16x8 vb[8];
#pragma unroll
    for (int kc = 0; kc < 2; ++kc)
#pragma unroll
      for (int dt = 0; dt < 4; ++dt)
        vb[kc * 4 + dt] =
            *(const bf16x8*)(vfb + (size_t)(dt * 16) * TT + j0 + kc * 32);

    const bool diag = (j0 == q0);
    const int rowbase = q0 + wave * 16 + quad * 4;
#pragma unroll
    for (int r = 0; r < 4; ++r) {
      int qrow = rowbase + r;
      float sv[4];
#pragma unroll
      for (int ct = 0; ct < 4; ++ct) {
        float s = s_acc[ct][r];
        if (diag && (j0 + ct * 16 + l15) > qrow) s = -INFINITY;
        sv[ct] = s;
      }
      float mt = fmaxf(fmaxf(sv[0], sv[1]), fmaxf(sv[2], sv[3]));
      mt = fmaxf(mt, __shfl_xor(mt, 1));
      mt = fmaxf(mt, __shfl_xor(mt, 2));
      mt = fmaxf(mt, __shfl_xor(mt, 4));
      mt = fmaxf(mt, __shfl_xor(mt, 8));
      float mnew = fmaxf(m_run[r], mt);
      float alpha = __expf(m_run[r] - mnew);
      float psum = 0.f;
      int prow = (wave * 16 + quad * 4 + r) * 72;
#pragma unroll
      for (int ct = 0; ct < 4; ++ct) {
        float p = __expf(sv[ct] - mnew);
        psum += p;
        Ps[prow + ct * 16 + l15] = f2bf(p);
      }
      psum += __shfl_xor(psum, 1);
      psum += __shfl_xor(psum, 2);
      psum += __shfl_xor(psum, 4);
      psum += __shfl_xor(psum, 8);
      l_run[r] = l_run[r] * alpha + psum;
      m_run[r] = mnew;
#pragma unroll
      for (int dt = 0; dt < 4; ++dt) o_acc[dt][r] *= alpha;
    }

    // PV (Ps rows are wave-private: lgkmcnt orders within-wave, no barrier)
    __builtin_amdgcn_s_setprio(1);
#pragma unroll
    for (int kc = 0; kc < 2; ++kc) {
      bf16x8 a = *(const bf16x8*)&Ps[(wave * 16 + l15) * 72 + kc * 32 + koff];
#pragma unroll
      for (int dt = 0; dt < 4; ++dt)
        o_acc[dt] = __builtin_amdgcn_mfma_f32_16x16x32_bf16(a, vb[kc * 4 + dt],
                                                            o_acc[dt], 0, 0, 0);
    }
    __builtin_amdgcn_s_setprio(0);
  }

#pragma unroll
  for (int dt = 0; dt < 4; ++dt) {
#pragma unroll
    for (int r = 0; r < 4; ++r) {
      int row = wave * 16 + quad * 4 + r;
      int t = q0 + row;
      int d = dt * 16 + l15;
      float o = o_acc[dt][r] / l_run[r];
      att[(((size_t)b * TT + t) * HH + h) * DD + d] = f2bf(o);
    }
  }
}

// ---------------------------------------------------------------------------
// Kernel 3: output projection  out[M,384] = att @ Wo + bo
// 2-phase double-buffered template + XCD swizzle (1536 = 8 * 64 * 3).
// ---------------------------------------------------------------------------
__global__ __launch_bounds__(256, 2) void oproj128_kernel(const unsigned short* __restrict__ A,
                                                          const unsigned short* __restrict__ Wot,
                                                          const float* __restrict__ bo,
                                                          float* __restrict__ out) {
  const int L = blockIdx.x;
  const int xcd = L & 7;
  const int j = L >> 3;                 // 0..191
  const int mt = xcd * 64 + j / 3;      // 0..511
  const int bx = j % 3;
  const int m0 = mt * 128;
  const int n0 = bx * 128;

  __shared__ char smem[65536];

  const int tid = threadIdx.x;
  const int wave = tid >> 6, lane = tid & 63;
  const int l15 = lane & 15, quad = lane >> 4;
  const int wm = (wave & 1) * 64, wn = (wave >> 1) * 64;
  const int xs = l15 & 7;

  f32x4 acc[4][4];
#pragma unroll
  for (int i = 0; i < 4; ++i)
#pragma unroll
    for (int jj = 0; jj < 4; ++jj) acc[i][jj] = (f32x4){0.f, 0.f, 0.f, 0.f};

  const int rl_base = wave * 32 + (lane >> 3);
  const int sb = lane & 7;

  STAGE_T(0, 0, Wot);
  __syncthreads();
#pragma unroll
  for (int it = 0; it < 6; ++it) {
    if (it < 5) STAGE_T((it & 1) ^ 1, (it + 1) * 64, Wot);
    COMPUTE_T(it & 1);
    __syncthreads();
  }

#pragma unroll
  for (int ni = 0; ni < 4; ++ni) {
    int c = n0 + wn + ni * 16 + l15;
    float bias = bo[c];
#pragma unroll
    for (int mi = 0; mi < 4; ++mi)
#pragma unroll
      for (int r = 0; r < 4; ++r) {
        int m = m0 + wm + mi * 16 + quad * 4 + r;
        out[(size_t)m * EE + c] = acc[mi][ni][r] + bias;
      }
  }
}

// ---------------------------------------------------------------------------
extern "C" void kernel_launch(void* const* d_in, const int* in_sizes, int n_in,
                              void* d_out, int out_size, void* d_ws, size_t ws_size,
                              hipStream_t stream) {
  const float* x  = (const float*)d_in[0];
  const float* Wq = (const float*)d_in[1];
  const float* Wk = (const float*)d_in[2];
  const float* Wv = (const float*)d_in[3];
  const float* Wo = (const float*)d_in[4];
  const float* bo = (const float*)d_in[5];
  float* out = (float*)d_out;

  char* ws = (char*)d_ws;
  const size_t SZ = (size_t)BB * TT * EE * 2;       // 48 MiB
  const size_t SQ = (size_t)BB * HH * TT * DD * 2;  // 48 MiB
  unsigned short* xb = (unsigned short*)ws;          // [B*T, E] bf16
  unsigned short* q  = (unsigned short*)(ws + SZ);
  unsigned short* k  = (unsigned short*)(ws + SZ + SQ);
  unsigned short* v  = (unsigned short*)(ws + SZ + 2 * SQ);
  unsigned short* Wt = (unsigned short*)(ws + SZ + 3 * SQ);  // [1536][384] bf16
  unsigned short* att = xb;  // xb dead after qkv; reuse for attention output

  prep_kernel<<<CVT_BLOCKS + 2304, 256, 0, stream>>>(x, Wq, Wk, Wv, Wo, xb, Wt);
  qkv128_kernel<<<dim3(9 * (BB * TT) / 128), 256, 0, stream>>>(xb, Wt, q, k, v);
  attn_kernel<<<dim3(BB * HH * TT / 64), 256, 0, stream>>>(q, k, v, att);
  oproj128_kernel<<<dim3(3 * (BB * TT) / 128), 256, 0, stream>>>(att, Wt + 1152 * 384, bo, out);
}

// Round 7
// 339.370 us; speedup vs baseline: 1.3894x; 1.3894x over previous
//
#include <hip/hip_runtime.h>
#include <hip/hip_bf16.h>
#include <math.h>

// Problem constants
#define BB 256
#define TT 256
#define EE 384
#define HH 6
#define DD 64

typedef __attribute__((ext_vector_type(8))) short bf16x8;
typedef __attribute__((ext_vector_type(4))) float f32x4;

__device__ inline unsigned short f2bf(float f) {
  unsigned int u = __builtin_bit_cast(unsigned int, f);
  u += 0x7fffu + ((u >> 16) & 1u);
  return (unsigned short)(u >> 16);
}

__device__ __forceinline__ void g2l16(const unsigned short* g, unsigned short* l) {
  // async global -> LDS, 16B per lane; LDS dest = wave-uniform base + lane*16
  __builtin_amdgcn_global_load_lds(
      (const __attribute__((address_space(1))) void*)g,
      (__attribute__((address_space(3))) void*)l, 16, 0, 0);
}

// ---------------------------------------------------------------------------
// Kernel 0: fused prep. Blocks [0, 24576): fp32->bf16 convert of x.
// Blocks [24576, 26880): weight prep Wt[1536][384] bf16.
// ---------------------------------------------------------------------------
#define CVT_BLOCKS 24576   // (BB*TT*EE/4) / 256
__global__ __launch_bounds__(256) void prep_kernel(const float* __restrict__ x,
                                                   const float* __restrict__ Wq,
                                                   const float* __restrict__ Wk,
                                                   const float* __restrict__ Wv,
                                                   const float* __restrict__ Wo,
                                                   unsigned short* __restrict__ xb,
                                                   unsigned short* __restrict__ Wt) {
  int bid = blockIdx.x;
  if (bid < CVT_BLOCKS) {
    int i = bid * 256 + threadIdx.x;      // exact: CVT_BLOCKS*256 == n4
    float4 f = ((const float4*)x)[i];
    ushort4 o;
    o.x = f2bf(f.x); o.y = f2bf(f.y); o.z = f2bf(f.z); o.w = f2bf(f.w);
    ((ushort4*)xb)[i] = o;
  } else {
    int idx = (bid - CVT_BLOCKS) * 256 + threadIdx.x;  // exact: 2304*256 == 1536*384
    int n = idx / 384, k = idx % 384;
    float val;
    if (n < 1152) {
      int mat = n / 384;
      int c = n % 384;
      int h = c >> 6, d = c & 63;
      const float* W = (mat == 0) ? Wq : (mat == 1 ? Wk : Wv);
      val = W[((size_t)h * EE + k) * DD + d];
    } else {
      int c = n - 1152;
      val = Wo[(size_t)k * EE + c];
    }
    Wt[idx] = f2bf(val);
  }
}

// ---------------------------------------------------------------------------
// Shared GEMM-tile macros: 128x128 tile, BK=64, XOR-swizzled LDS,
// double-buffered (2-phase pipeline).  Both operands via global_load_lds.
// ---------------------------------------------------------------------------
#define STAGE_T(buf, k0, Bsrc)                                                  \
  do {                                                                          \
    unsigned short* As_ = (unsigned short*)(smem + (buf) * 32768);              \
    unsigned short* Bs_ = As_ + 8192;                                           \
    _Pragma("unroll") for (int i = 0; i < 4; ++i) {                             \
      int rl = rl_base + i * 8;                                                 \
      int gcb = sb ^ (rl & 7);                                                  \
      g2l16(A + (size_t)(m0 + rl) * EE + (k0) + gcb * 8,                        \
            &As_[(wave * 32 + i * 8) * 64]);                                    \
    }                                                                           \
    _Pragma("unroll") for (int i = 0; i < 4; ++i) {                             \
      int rl = rl_base + i * 8;                                                 \
      int gcb = sb ^ (rl & 7);                                                  \
      g2l16((Bsrc) + (size_t)(n0 + rl) * EE + (k0) + gcb * 8,                   \
            &Bs_[(wave * 32 + i * 8) * 64]);                                    \
    }                                                                           \
  } while (0)

#define COMPUTE_T(buf)                                                          \
  do {                                                                          \
    const unsigned short* As_ = (const unsigned short*)(smem + (buf) * 32768);  \
    const unsigned short* Bs_ = As_ + 8192;                                     \
    _Pragma("unroll") for (int kc = 0; kc < 2; ++kc) {                          \
      bf16x8 af[4], bfr[4];                                                     \
      _Pragma("unroll") for (int mi = 0; mi < 4; ++mi)                          \
          af[mi] = *(const bf16x8*)&As_[(wm + mi * 16 + l15) * 64 +             \
                                        ((kc * 4 + quad) ^ xs) * 8];            \
      _Pragma("unroll") for (int ni = 0; ni < 4; ++ni)                          \
          bfr[ni] = *(const bf16x8*)&Bs_[(wn + ni * 16 + l15) * 64 +            \
                                         ((kc * 4 + quad) ^ xs) * 8];           \
      _Pragma("unroll") for (int mi = 0; mi < 4; ++mi)                          \
          _Pragma("unroll") for (int ni = 0; ni < 4; ++ni)                      \
              acc[mi][ni] = __builtin_amdgcn_mfma_f32_16x16x32_bf16(            \
                  af[mi], bfr[ni], acc[mi][ni], 0, 0, 0);                       \
    }                                                                           \
  } while (0)

// ---------------------------------------------------------------------------
// Kernel 1: fused QKV GEMM (unchanged from R2/R4 measured-good version).
// ---------------------------------------------------------------------------
__global__ __launch_bounds__(256, 2) void qkv128_kernel(const unsigned short* __restrict__ A,
                                                        const unsigned short* __restrict__ Wt,
                                                        unsigned short* __restrict__ q,
                                                        unsigned short* __restrict__ k,
                                                        unsigned short* __restrict__ v) {
  const int L = blockIdx.x;
  const int xcd = L & 7;
  const int j = L >> 3;                 // 0..575
  const int mt = xcd * 64 + j / 9;      // 0..511
  const int bx = j % 9;                 // n-tile
  const int m0 = mt * 128;
  const int n0 = bx * 128;

  __shared__ char smem[65536];
  unsigned short* bounce = (unsigned short*)smem;

  const int tid = threadIdx.x;
  const int wave = tid >> 6, lane = tid & 63;
  const int l15 = lane & 15, quad = lane >> 4;
  const int wm = (wave & 1) * 64, wn = (wave >> 1) * 64;
  const int xs = l15 & 7;

  f32x4 acc[4][4];
#pragma unroll
  for (int i = 0; i < 4; ++i)
#pragma unroll
    for (int jj = 0; jj < 4; ++jj) acc[i][jj] = (f32x4){0.f, 0.f, 0.f, 0.f};

  const int rl_base = wave * 32 + (lane >> 3);
  const int sb = lane & 7;

  STAGE_T(0, 0, Wt);
  __syncthreads();
#pragma unroll
  for (int it = 0; it < 6; ++it) {
    if (it < 5) STAGE_T((it & 1) ^ 1, (it + 1) * 64, Wt);
    COMPUTE_T(it & 1);
    __syncthreads();
  }

  const int b = m0 >> 8;
  const int t0 = m0 & 255;

  if (bx < 6) {
    unsigned short* outp = (bx < 3) ? q : k;
    const float qs = (bx < 3) ? 0.125f : 1.0f;
    const int cmbase = n0 - (bx < 3 ? 0 : 384);
#pragma unroll
    for (int ni = 0; ni < 4; ++ni) {
      int c = cmbase + wn + ni * 16 + l15;
      int h = c >> 6, d = c & 63;
#pragma unroll
      for (int mi = 0; mi < 4; ++mi)
#pragma unroll
        for (int r = 0; r < 4; ++r) {
          int t = t0 + wm + mi * 16 + quad * 4 + r;
          outp[(((size_t)b * HH + h) * TT + t) * DD + d] = f2bf(acc[mi][ni][r] * qs);
        }
    }
  } else {
#pragma unroll
    for (int pass = 0; pass < 2; ++pass) {
      __syncthreads();
      if ((wave >> 1) == pass) {
#pragma unroll
        for (int ni = 0; ni < 4; ++ni) {
          int cl = ni * 16 + l15;
#pragma unroll
          for (int mi = 0; mi < 4; ++mi)
#pragma unroll
            for (int r = 0; r < 4; ++r) {
              int rloc = wm + mi * 16 + quad * 4 + r;
              bounce[cl * 136 + rloc] = f2bf(acc[mi][ni][r]);
            }
        }
      }
      __syncthreads();
      int h = (bx - 6) * 2 + pass;
      int d = tid >> 2;
      int tb = (tid & 3) * 32;
      unsigned short* vdst = v + (((size_t)b * HH + h) * DD + d) * TT + t0 + tb;
      const unsigned short* bsrc = &bounce[d * 136 + tb];
#pragma unroll
      for (int jj = 0; jj < 4; ++jj)
        *(uint4*)(vdst + jj * 8) = *(const uint4*)(bsrc + jj * 8);
    }
  }
}

// ---------------------------------------------------------------------------
// Kernel 2: flash-style causal attention — R7: one block per (b,h), 8 waves.
// K[256][64] and V^T[64][256] staged in LDS ONCE (XOR-swizzled, gload_lds),
// then a SINGLE __syncthreads for the whole kernel; all waves self-paced.
// R7 fix vs R6: g2l16 stages exactly 8 rows of [64] bf16 (1024 B) per call,
// so K uses 32 groups of 8 rows (4 calls/wave) — R6's 16-row groups left
// 1024-B holes (half of Ks unwritten -> correctness failure).
// Exact causal balance: wave w owns q-chunks {w, 15-w} -> 5 k-tiles each.
// Ps is per-wave [16][64] XOR-swizzled. LDS total = 80 KB -> 2 blocks/CU.
// ---------------------------------------------------------------------------
__global__ __launch_bounds__(512, 4) void attn_kernel(const unsigned short* __restrict__ q,
                                                      const unsigned short* __restrict__ k,
                                                      const unsigned short* __restrict__ v,
                                                      unsigned short* __restrict__ att) {
  const int L = blockIdx.x;
  const int bh = (L & 7) * 192 + (L >> 3);   // XCD-contiguous, bijective (1536=8*192)
  const int b = bh / HH, h = bh % HH;

  __shared__ unsigned short Ks[256 * 64];    // 32 KB: Ks[row][c] = K[row][c^(row&7)]
  __shared__ unsigned short Vt[64 * 256];    // 32 KB: Vt[d][c] = V^T[d][(c&24)|((c&7)^(d&7))]
  __shared__ unsigned short Ps[8 * 16 * 64]; // 16 KB: per-wave [16][chunk^row&7]

  const int tid = threadIdx.x;
  const int wave = tid >> 6, lane = tid & 63;
  const int l15 = lane & 15, quad = lane >> 4;
  const int koff = quad * 8;

  // ---- stage K: 32 groups of 8 rows; wave w does groups {4w..4w+3} ----
#pragma unroll
  for (int p = 0; p < 4; ++p) {
    int grp = wave * 4 + p;                  // 0..31
    int row = grp * 8 + (lane >> 3);         // 8 rows per call
    int gch = (lane & 7) ^ (row & 7);
    g2l16(k + ((size_t)bh * TT + row) * DD + gch * 8, &Ks[grp * 8 * 64]);
  }
  // ---- stage V^T: 32 groups of 2 rows; wave w does groups {4w..4w+3} ----
#pragma unroll
  for (int p = 0; p < 4; ++p) {
    int grp = wave * 4 + p;
    int d = grp * 2 + (lane >> 5);
    int c = lane & 31;
    int gch = (c & 24) | ((c & 7) ^ (d & 7));
    g2l16(v + ((size_t)bh * DD + d) * TT + gch * 8, &Vt[grp * 2 * 256]);
  }
  __syncthreads();   // the ONLY barrier

  unsigned short* Pw = Ps + wave * 1024;   // this wave's [16][64]

  // two q-chunks per wave: {wave, 15-wave} -> exactly 5 k-tiles total
#pragma unroll
  for (int cc = 0; cc < 2; ++cc) {
    const int c = cc ? (15 - wave) : wave;   // q-chunk index (16 rows)
    const int ntiles = (c >> 2) + 1;

    // Q fragments for this chunk (q pre-scaled by 1/8 upstream)
    bf16x8 aq[2];
    {
      const unsigned short* qrow =
          q + ((size_t)bh * TT + c * 16 + l15) * DD + koff;
      aq[0] = *(const bf16x8*)(qrow);
      aq[1] = *(const bf16x8*)(qrow + 32);
    }

    f32x4 o_acc[4] = {{0.f,0.f,0.f,0.f},{0.f,0.f,0.f,0.f},{0.f,0.f,0.f,0.f},{0.f,0.f,0.f,0.f}};
    float m_run[4] = {-INFINITY, -INFINITY, -INFINITY, -INFINITY};
    float l_run[4] = {0.f, 0.f, 0.f, 0.f};

    for (int jt = 0; jt < ntiles; ++jt) {
      const int j0 = jt * 64;

      // QK^T from swizzled Ks
      f32x4 s_acc[4] = {{0.f,0.f,0.f,0.f},{0.f,0.f,0.f,0.f},{0.f,0.f,0.f,0.f},{0.f,0.f,0.f,0.f}};
      __builtin_amdgcn_s_setprio(1);
#pragma unroll
      for (int kc = 0; kc < 2; ++kc)
#pragma unroll
        for (int ct = 0; ct < 4; ++ct) {
          int row = j0 + ct * 16 + l15;
          bf16x8 bb = *(const bf16x8*)&Ks[row * 64 + (((kc * 4 + quad) ^ (row & 7)) * 8)];
          s_acc[ct] = __builtin_amdgcn_mfma_f32_16x16x32_bf16(aq[kc], bb, s_acc[ct], 0, 0, 0);
        }
      __builtin_amdgcn_s_setprio(0);

      const bool diag = (jt == (c >> 2));
      const int rowbase = c * 16 + quad * 4;
#pragma unroll
      for (int r = 0; r < 4; ++r) {
        int qrow = rowbase + r;
        float sv[4];
#pragma unroll
        for (int ct = 0; ct < 4; ++ct) {
          float s = s_acc[ct][r];
          if (diag && (j0 + ct * 16 + l15) > qrow) s = -INFINITY;
          sv[ct] = s;
        }
        float mt = fmaxf(fmaxf(sv[0], sv[1]), fmaxf(sv[2], sv[3]));
        mt = fmaxf(mt, __shfl_xor(mt, 1));
        mt = fmaxf(mt, __shfl_xor(mt, 2));
        mt = fmaxf(mt, __shfl_xor(mt, 4));
        mt = fmaxf(mt, __shfl_xor(mt, 8));
        float mnew = fmaxf(m_run[r], mt);
        float alpha = __expf(m_run[r] - mnew);
        float psum = 0.f;
        int pr = quad * 4 + r;
#pragma unroll
        for (int ct = 0; ct < 4; ++ct) {
          float p = __expf(sv[ct] - mnew);
          psum += p;
          int chunk = (ct * 2 + (l15 >> 3)) ^ (pr & 7);
          Pw[pr * 64 + chunk * 8 + (l15 & 7)] = f2bf(p);
        }
        psum += __shfl_xor(psum, 1);
        psum += __shfl_xor(psum, 2);
        psum += __shfl_xor(psum, 4);
        psum += __shfl_xor(psum, 8);
        l_run[r] = l_run[r] * alpha + psum;
        m_run[r] = mnew;
#pragma unroll
        for (int dt = 0; dt < 4; ++dt) o_acc[dt][r] *= alpha;
      }

      // PV from per-wave Ps (wave-private; lgkmcnt orders) and swizzled Vt
      __builtin_amdgcn_s_setprio(1);
#pragma unroll
      for (int kc = 0; kc < 2; ++kc) {
        bf16x8 a = *(const bf16x8*)&Pw[l15 * 64 + (((kc * 4 + quad) ^ (l15 & 7)) * 8)];
#pragma unroll
        for (int dt = 0; dt < 4; ++dt) {
          int d = dt * 16 + l15;
          int phys = (j0 >> 3) + ((kc * 4 + quad) ^ (d & 7));
          bf16x8 bb = *(const bf16x8*)&Vt[d * 256 + phys * 8];
          o_acc[dt] = __builtin_amdgcn_mfma_f32_16x16x32_bf16(a, bb, o_acc[dt], 0, 0, 0);
        }
      }
      __builtin_amdgcn_s_setprio(0);
    }

    // write this chunk's output
#pragma unroll
    for (int dt = 0; dt < 4; ++dt) {
#pragma unroll
      for (int r = 0; r < 4; ++r) {
        int t = c * 16 + quad * 4 + r;
        int d = dt * 16 + l15;
        float o = o_acc[dt][r] / l_run[r];
        att[(((size_t)b * TT + t) * HH + h) * DD + d] = f2bf(o);
      }
    }
  }
}

// ---------------------------------------------------------------------------
// Kernel 3: output projection  out[M,384] = att @ Wo + bo  (unchanged).
// ---------------------------------------------------------------------------
__global__ __launch_bounds__(256, 2) void oproj128_kernel(const unsigned short* __restrict__ A,
                                                          const unsigned short* __restrict__ Wot,
                                                          const float* __restrict__ bo,
                                                          float* __restrict__ out) {
  const int L = blockIdx.x;
  const int xcd = L & 7;
  const int j = L >> 3;
  const int mt = xcd * 64 + j / 3;
  const int bx = j % 3;
  const int m0 = mt * 128;
  const int n0 = bx * 128;

  __shared__ char smem[65536];

  const int tid = threadIdx.x;
  const int wave = tid >> 6, lane = tid & 63;
  const int l15 = lane & 15, quad = lane >> 4;
  const int wm = (wave & 1) * 64, wn = (wave >> 1) * 64;
  const int xs = l15 & 7;

  f32x4 acc[4][4];
#pragma unroll
  for (int i = 0; i < 4; ++i)
#pragma unroll
    for (int jj = 0; jj < 4; ++jj) acc[i][jj] = (f32x4){0.f, 0.f, 0.f, 0.f};

  const int rl_base = wave * 32 + (lane >> 3);
  const int sb = lane & 7;

  STAGE_T(0, 0, Wot);
  __syncthreads();
#pragma unroll
  for (int it = 0; it < 6; ++it) {
    if (it < 5) STAGE_T((it & 1) ^ 1, (it + 1) * 64, Wot);
    COMPUTE_T(it & 1);
    __syncthreads();
  }

#pragma unroll
  for (int ni = 0; ni < 4; ++ni) {
    int c = n0 + wn + ni * 16 + l15;
    float bias = bo[c];
#pragma unroll
    for (int mi = 0; mi < 4; ++mi)
#pragma unroll
      for (int r = 0; r < 4; ++r) {
        int m = m0 + wm + mi * 16 + quad * 4 + r;
        out[(size_t)m * EE + c] = acc[mi][ni][r] + bias;
      }
  }
}

// ---------------------------------------------------------------------------
extern "C" void kernel_launch(void* const* d_in, const int* in_sizes, int n_in,
                              void* d_out, int out_size, void* d_ws, size_t ws_size,
                              hipStream_t stream) {
  const float* x  = (const float*)d_in[0];
  const float* Wq = (const float*)d_in[1];
  const float* Wk = (const float*)d_in[2];
  const float* Wv = (const float*)d_in[3];
  const float* Wo = (const float*)d_in[4];
  const float* bo = (const float*)d_in[5];
  float* out = (float*)d_out;

  char* ws = (char*)d_ws;
  const size_t SZ = (size_t)BB * TT * EE * 2;       // 48 MiB
  const size_t SQ = (size_t)BB * HH * TT * DD * 2;  // 48 MiB
  unsigned short* xb = (unsigned short*)ws;          // [B*T, E] bf16
  unsigned short* q  = (unsigned short*)(ws + SZ);
  unsigned short* k  = (unsigned short*)(ws + SZ + SQ);
  unsigned short* v  = (unsigned short*)(ws + SZ + 2 * SQ);
  unsigned short* Wt = (unsigned short*)(ws + SZ + 3 * SQ);  // [1536][384] bf16
  unsigned short* att = xb;  // xb dead after qkv; reuse for attention output

  prep_kernel<<<CVT_BLOCKS + 2304, 256, 0, stream>>>(x, Wq, Wk, Wv, Wo, xb, Wt);
  qkv128_kernel<<<dim3(9 * (BB * TT) / 128), 256, 0, stream>>>(xb, Wt, q, k, v);
  attn_kernel<<<dim3(BB * HH), 512, 0, stream>>>(q, k, v, att);
  oproj128_kernel<<<dim3(3 * (BB * TT) / 128), 256, 0, stream>>>(att, Wt + 1152 * 384, bo, out);
}